// Round 3
// baseline (1135.332 us; speedup 1.0000x reference)
//
#include <hip/hip_runtime.h>
#include <hip/hip_fp16.h>
#include <cstdint>
#include <cstddef>

#define BB 128
#define NN 1024
#define NI 64
#define TT 512
#define MAXNNZ 16384
#define NE 28
#define TH 16

// ws layout (bytes)
#define WS_XSTATE 0u        // [BB*NN] f32 = 524288
#define WS_OFFS   524288u   // int[1025]
#define WS_CNT    532480u   // int[1024]
#define WS_IDX    536576u   // u16[MAXNNZ] = 32768
#define WS_VAL    569344u   // f32[MAXNNZ] = 65536
#define WS_PERM   634880u   // int[1024]
#define WS_IPERM  638976u   // int[1024]
#define WS_U      1048576u  // U chunk [Tc*BB*NN] fp16

// ---------- sparse build ----------
__global__ __launch_bounds__(64) void k_count(const float* __restrict__ W, int* __restrict__ cnt) {
    int col = blockIdx.x * 64 + threadIdx.x;
    int c = 0;
    for (int k = 0; k < NN; ++k) c += (W[(size_t)k * NN + col] != 0.0f) ? 1 : 0;
    cnt[col] = c;
}

__global__ __launch_bounds__(1024) void k_scan(const int* __restrict__ cnt, int* __restrict__ offs) {
    __shared__ int s[NN];
    int tid = threadIdx.x;
    s[tid] = cnt[tid];
    __syncthreads();
    for (int d = 1; d < NN; d <<= 1) {
        int v = (tid >= d) ? s[tid - d] : 0;
        __syncthreads();
        s[tid] += v;
        __syncthreads();
    }
    int incl = s[tid];
    offs[tid + 1] = (incl < MAXNNZ) ? incl : MAXNNZ;
    if (tid == 0) offs[0] = 0;
}

__global__ __launch_bounds__(64) void k_fill(const float* __restrict__ W, const int* __restrict__ offs,
                                             unsigned short* __restrict__ idx, float* __restrict__ val) {
    int col = blockIdx.x * 64 + threadIdx.x;
    int pos = offs[col];
    int end = offs[col + 1];
    for (int k = 0; k < NN; ++k) {
        float w = W[(size_t)k * NN + col];
        if (w != 0.0f) {
            if (pos < end) { idx[pos] = (unsigned short)k; val[pos] = w; ++pos; }
        }
    }
}

// rank columns by entry count (descending, stable) -> perm/iperm
__global__ __launch_bounds__(1024) void k_rank(const int* __restrict__ offs,
                                               int* __restrict__ perm, int* __restrict__ iperm) {
    __shared__ int sc[NN];
    int n = threadIdx.x;
    sc[n] = offs[n + 1] - offs[n];
    __syncthreads();
    int myc = sc[n];
    int r = 0;
    for (int m = 0; m < NN; ++m) {
        int cm = sc[m];                 // broadcast read (uniform m)
        r += (cm > myc || (cm == myc && m < n)) ? 1 : 0;
    }
    perm[r] = n;
    iperm[n] = r;
}

// ---------- input projection: U[tt][b][n] = sum_i In[b][i][t0+tt] * Win[i][n], fp16 out ----------
__global__ __launch_bounds__(256) void k_uproj(const float* __restrict__ In, const float* __restrict__ Win,
                                               __half* __restrict__ U, int t0) {
    int tt = blockIdx.x >> 2;
    int bq = blockIdx.x & 3;
    int t  = t0 + tt;
    int b0 = bq * 32;
    __shared__ float s[32][NI];
    int tid = threadIdx.x;
    for (int q = tid; q < 32 * NI; q += 256) {
        int j = q >> 6, i = q & 63;
        s[j][i] = In[((size_t)(b0 + j) * NI + i) * TT + t];
    }
    __syncthreads();
    const float4* W4 = (const float4*)Win;
    uint2* U2 = (uint2*)U;
    for (int bt = 0; bt < 32; bt += 8) {
        float4 acc[8];
#pragma unroll
        for (int j = 0; j < 8; ++j) acc[j] = make_float4(0.f, 0.f, 0.f, 0.f);
        for (int i = 0; i < NI; ++i) {
            float4 w = W4[i * (NN / 4) + tid];
#pragma unroll
            for (int j = 0; j < 8; ++j) {
                float sv = s[bt + j][i];
                acc[j].x = fmaf(w.x, sv, acc[j].x);
                acc[j].y = fmaf(w.y, sv, acc[j].y);
                acc[j].z = fmaf(w.z, sv, acc[j].z);
                acc[j].w = fmaf(w.w, sv, acc[j].w);
            }
        }
#pragma unroll
        for (int j = 0; j < 8; ++j) {
            float ax = fminf(fmaxf(acc[j].x, -60000.f), 60000.f);
            float ay = fminf(fmaxf(acc[j].y, -60000.f), 60000.f);
            float az = fminf(fmaxf(acc[j].z, -60000.f), 60000.f);
            float aw = fminf(fmaxf(acc[j].w, -60000.f), 60000.f);
            __half2 h01 = __floats2half2_rn(ax, ay);
            __half2 h23 = __floats2half2_rn(az, aw);
            uint2 pk;
            pk.x = *(unsigned int*)&h01;
            pk.y = *(unsigned int*)&h23;
            U2[((size_t)tt * BB + (b0 + bt + j)) * (NN / 4) + tid] = pk;
        }
    }
}

// ---------- recurrence ----------
__device__ __forceinline__ float fast_tanh(float z) {
    float a = fabsf(z) * 2.885390082f;       // 2*log2(e)
    a = fminf(a, 60.0f);
    float e = __builtin_amdgcn_exp2f(a);     // e^{2|z|}
    float r = 1.0f - __fdividef(2.0f, e + 1.0f);
    return z < 0.0f ? -r : r;
}

__global__ __launch_bounds__(1024) void k_step(const __half* __restrict__ U,
        const int* __restrict__ offs, const unsigned short* __restrict__ gidx,
        const float* __restrict__ gval, const int* __restrict__ perm,
        const int* __restrict__ iperm, float* __restrict__ out,
        float* __restrict__ xstate, int t0, int Tc) {
    // ping-pong x, 2 copies each: [buf][copy][NN] = 16 KB
    __shared__ float xbuf[2][2][NN];
    int b = blockIdx.x, tid = threadIdx.x;
    int c = perm[tid];                       // this thread's column

    int o0 = offs[c];
    int cnt = offs[c + 1] - o0;
    float wv[NE];
    int ka[NE];
#pragma unroll
    for (int j = 0; j < NE; ++j) {
        if (j < cnt) { wv[j] = gval[o0 + j]; ka[j] = iperm[(int)gidx[o0 + j]] << 2; }
        else         { wv[j] = 0.0f;         ka[j] = 0; }
    }
    // wave-uniform max entry count (tight after count-sorted assignment)
    int wmax = cnt;
#pragma unroll
    for (int d = 1; d < 64; d <<= 1) {
        int o = __shfl_xor(wmax, d);
        wmax = wmax > o ? wmax : o;
    }
    wmax = __builtin_amdgcn_readfirstlane(wmax);

    float x = (t0 == 0) ? 0.0f : xstate[((size_t)b << 10) + tid];
    xbuf[0][0][tid] = x;
    xbuf[0][1][tid] = x;
    __syncthreads();

    const __half* Ub = U + (size_t)b * NN + c;
    const size_t ustep = (size_t)BB * NN;
    const char* xb = (const char*)&xbuf[0][0][0];
    const int hofs = ((tid >> 5) & 1) << 12; // which copy this half-wave reads
    float unx = __half2float(Ub[0]);

    for (int tb = 0; tb < Tc; tb += TH) {
        float xh[TH];
#pragma unroll
        for (int tt = 0; tt < TH; ++tt) {
            int t = tb + tt;
            float u = unx;
            if (t + 1 < Tc) unx = __half2float(Ub[(size_t)(t + 1) * ustep]);

            const int phr = (t & 1) << 13;   // read buffer
            float z = u;
#pragma unroll
            for (int j = 0; j < NE; ++j) {
                if (j < wmax) {
                    float xv = *(const float*)(xb + phr + hofs + ka[j]);
                    z = fmaf(wv[j], xv, z);
                }
            }
            x = 0.5f * x + 0.5f * fast_tanh(z);
            xh[tt] = x;
            float* wb = (float*)(xb + (phr ^ (1 << 13)));  // write other buffer, both copies
            wb[tid] = x;
            wb[NN + tid] = x;
            __syncthreads();
        }
        // dump 16 steps: 64 B contiguous per thread
        float4* op = (float4*)(out + ((size_t)b * NN + c) * TT + (size_t)(t0 + tb));
        op[0] = make_float4(xh[0],  xh[1],  xh[2],  xh[3]);
        op[1] = make_float4(xh[4],  xh[5],  xh[6],  xh[7]);
        op[2] = make_float4(xh[8],  xh[9],  xh[10], xh[11]);
        op[3] = make_float4(xh[12], xh[13], xh[14], xh[15]);
    }
    xstate[((size_t)b << 10) + tid] = x;
}

extern "C" void kernel_launch(void* const* d_in, const int* in_sizes, int n_in,
                              void* d_out, int out_size, void* d_ws, size_t ws_size,
                              hipStream_t stream) {
    const float* In  = (const float*)d_in[0];
    const float* W   = (const float*)d_in[1];
    const float* Win = (const float*)d_in[2];
    float* out = (float*)d_out;
    char* ws = (char*)d_ws;
    float* xstate       = (float*)(ws + WS_XSTATE);
    int* offs           = (int*)(ws + WS_OFFS);
    int* cnt            = (int*)(ws + WS_CNT);
    unsigned short* idx = (unsigned short*)(ws + WS_IDX);
    float* val          = (float*)(ws + WS_VAL);
    int* perm           = (int*)(ws + WS_PERM);
    int* iperm          = (int*)(ws + WS_IPERM);
    __half* U           = (__half*)(ws + WS_U);

    // biggest U chunk (fp16) that fits in ws
    int Tc = 16;
    const int cands[6] = {512, 256, 128, 64, 32, 16};
    for (int i = 0; i < 6; ++i) {
        if ((size_t)WS_U + (size_t)cands[i] * BB * NN * 2 <= ws_size) { Tc = cands[i]; break; }
    }

    k_count<<<16, 64, 0, stream>>>(W, cnt);
    k_scan<<<1, 1024, 0, stream>>>(cnt, offs);
    k_fill<<<16, 64, 0, stream>>>(W, offs, idx, val);
    k_rank<<<1, 1024, 0, stream>>>(offs, perm, iperm);

    for (int t0 = 0; t0 < TT; t0 += Tc) {
        k_uproj<<<Tc * 4, 256, 0, stream>>>(In, Win, U, t0);
        k_step<<<BB, 1024, 0, stream>>>(U, offs, idx, val, perm, iperm, out, xstate, t0, Tc);
    }
}